// Round 4
// baseline (51.187 us; speedup 1.0000x reference)
//
#include <hip/hip_runtime.h>
#include <hip/hip_bf16.h>

// Problem: 4 embedding-table row gathers.
//   indices: rgap, sgap, pcount, prcount  int32 [128*500] = 64000 each
//   tables:  Wr, Ws, Wp, Wpr              f32   [100*256] (102.4 KB each)
//   output:  concat of 4x [64000, 256] f32 = 262 MB
//
// Write-BW-bound. History: R0 48.3us, R1 51.5us (nt + 32-deep unroll ->
// VGPR/occupancy cliff masked nt), R2 47.6us (two-phase idx prefetch,
// launch_bounds(256,4), normal stores).
//
// R3 = R2 + nontemporal stores ONLY (clean A/B). Theory: the 262 MB
// write stream allocates in L2, thrashing the 32 MB aggregate L2 and
// evicting the 410 KB of tables -> table reads stall the store pipe.
// nt stores keep the write stream out of L2; tables stay L2-hot.
// fillBuffer (7.0 TB/s) needs no nt because it has no read stream.

typedef float f32x4 __attribute__((ext_vector_type(4)));

#define ROWS        64000            // B*S
#define V4_ROW      64               // 256 f32 = 64 float4
#define V4_TAB      (ROWS * V4_ROW)  // 4,096,000 float4 per table
#define NTHREADS    512000           // 2000 blocks * 256
#define ITERS       8                // V4_TAB / NTHREADS, exact

__global__ __launch_bounds__(256, 4) void gather4_kernel(
    const int* __restrict__ i0, const int* __restrict__ i1,
    const int* __restrict__ i2, const int* __restrict__ i3,
    const f32x4* __restrict__ w0, const f32x4* __restrict__ w1,
    const f32x4* __restrict__ w2, const f32x4* __restrict__ w3,
    f32x4* __restrict__ out)
{
    const int* idx[4] = {i0, i1, i2, i3};
    const f32x4* w[4] = {w0, w1, w2, w3};

    const int tid = blockIdx.x * 256 + threadIdx.x;   // 0..511999

    // Phase 1: prefetch all row indices (32 independent 4B loads,
    // wave-uniform addresses -> broadcast hits in L1/L2).
    int id[ITERS][4];
#pragma unroll
    for (int k = 0; k < ITERS; ++k) {
        const int r = (tid + k * NTHREADS) >> 6;   // row, uniform per wave
#pragma unroll
        for (int t = 0; t < 4; ++t) id[k][t] = idx[t][r];
    }

    // Phase 2: table-row load -> nontemporal store stream.
#pragma unroll
    for (int k = 0; k < ITERS; ++k) {
        const int j = tid + k * NTHREADS;
        const int l = j & 63;                      // float4 slot within row
#pragma unroll
        for (int t = 0; t < 4; ++t) {
            const f32x4 v = w[t][id[k][t] * V4_ROW + l];  // L2-resident read
            __builtin_nontemporal_store(v, &out[(long)t * V4_TAB + j]);
        }
    }
}

extern "C" void kernel_launch(void* const* d_in, const int* in_sizes, int n_in,
                              void* d_out, int out_size, void* d_ws, size_t ws_size,
                              hipStream_t stream) {
    const int* rgap    = (const int*)d_in[0];
    const int* sgap    = (const int*)d_in[1];
    const int* pcount  = (const int*)d_in[2];
    const int* prcount = (const int*)d_in[3];
    const f32x4* Wr  = (const f32x4*)d_in[4];
    const f32x4* Ws  = (const f32x4*)d_in[5];
    const f32x4* Wp  = (const f32x4*)d_in[6];
    const f32x4* Wpr = (const f32x4*)d_in[7];
    f32x4* out = (f32x4*)d_out;

    gather4_kernel<<<2000, 256, 0, stream>>>(
        rgap, sgap, pcount, prcount, Wr, Ws, Wp, Wpr, out);
}

// Round 5
// 47.435 us; speedup vs baseline: 1.0791x; 1.0791x over previous
//
#include <hip/hip_runtime.h>
#include <hip/hip_bf16.h>

// Problem: 4 embedding-table row gathers.
//   indices: 4x int32 [64000], tables: 4x f32 [100][256] (102.4 KB each)
//   output:  concat 4x [64000, 256] f32 = 262 MB. Write-BW-bound.
//
// History: R0 48.3us | R1 51.5us (nt+deep unroll) | R2 47.6us (best; 2-phase
// idx prefetch) | R3 51.2us (R2+nt: nt stores are ~+3.5us harmful, refuted).
//
// R4: persistent per-table blocks with LDS-staged table + indices.
// Theory: every store in R2 carries a dependent L2 table read (L1 too small,
// random rows) riding the same TCC path as the 262 MB write stream; fill
// hits 7.0 TB/s with no read stream. Here the hot loop is LDS-read -> store
// only: 256 blocks (1/CU; LDS 106.4 KB/block), 512 thr, each block owns one
// 1000-row chunk of one table, writes exactly 1 MB; staging = 106 KB once.

typedef float f32x4 __attribute__((ext_vector_type(4)));

#define ROWS_TAB    64000            // B*S rows per table
#define V4_ROW      64               // 256 f32 = 64 float4
#define V4_TAB      (ROWS_TAB * V4_ROW)      // 4,096,000 float4 per table
#define TAB_V4      6400             // 100 rows * 64 float4 (102,400 B)
#define BLK_TABLES  64               // blocks per table
#define ROWS_BLK    1000             // 64000 / 64 rows per block
#define V4_BLK      64000            // ROWS_BLK * 64 float4 per block (1 MB)
#define THREADS     512
#define MAIN_ITERS  125              // V4_BLK / THREADS, exact

__global__ __launch_bounds__(THREADS, 1) void gather_lds_kernel(
    const int* __restrict__ i0, const int* __restrict__ i1,
    const int* __restrict__ i2, const int* __restrict__ i3,
    const f32x4* __restrict__ w0, const f32x4* __restrict__ w1,
    const f32x4* __restrict__ w2, const f32x4* __restrict__ w3,
    f32x4* __restrict__ out)
{
    __shared__ f32x4 tab[TAB_V4];    // 102,400 B — this block's table
    __shared__ int   ridx[ROWS_BLK]; //   4,000 B — this block's row indices

    const int b   = blockIdx.x;      // 0..255
    const int t   = b >> 6;          // table 0..3
    const int c   = b & 63;          // chunk within table
    const int tid = threadIdx.x;

    const int*   idx = (t == 0) ? i0 : (t == 1) ? i1 : (t == 2) ? i2 : i3;
    const f32x4* w   = (t == 0) ? w0 : (t == 1) ? w1 : (t == 2) ? w2 : w3;

    // Stage table (coalesced float4) and this chunk's indices.
    for (int i = tid; i < TAB_V4; i += THREADS) tab[i] = w[i];
    for (int i = tid; i < ROWS_BLK; i += THREADS) ridx[i] = idx[c * ROWS_BLK + i];
    __syncthreads();

    // Hot loop: LDS read -> coalesced global store. No global reads.
    f32x4* o = out + (long)t * V4_TAB + (long)c * V4_BLK;
#pragma unroll 5
    for (int it = 0; it < MAIN_ITERS; ++it) {
        const int jl = it * THREADS + tid;   // 0..63999
        const int r  = jl >> 6;              // local row (uniform per wave)
        const int l  = jl & 63;              // float4 slot in row
        o[jl] = tab[ridx[r] * V4_ROW + l];   // bcast idx + conflict-free b128
    }
}

extern "C" void kernel_launch(void* const* d_in, const int* in_sizes, int n_in,
                              void* d_out, int out_size, void* d_ws, size_t ws_size,
                              hipStream_t stream) {
    const int* rgap    = (const int*)d_in[0];
    const int* sgap    = (const int*)d_in[1];
    const int* pcount  = (const int*)d_in[2];
    const int* prcount = (const int*)d_in[3];
    const f32x4* Wr  = (const f32x4*)d_in[4];
    const f32x4* Ws  = (const f32x4*)d_in[5];
    const f32x4* Wp  = (const f32x4*)d_in[6];
    const f32x4* Wpr = (const f32x4*)d_in[7];
    f32x4* out = (f32x4*)d_out;

    gather_lds_kernel<<<256, THREADS, 0, stream>>>(
        rgap, sgap, pcount, prcount, Wr, Ws, Wp, Wpr, out);
}